// Round 2
// baseline (219.354 us; speedup 1.0000x reference)
//
#include <hip/hip_runtime.h>

// Problem constants (from setup_inputs): B=32, T=512, F=513, S=3
#define BB 32
#define TT 512
#define FF 513
#define SS 3
#define NN (TT * FF)                 // 262656 elements per (b, source)
#define FLOATS_PER_B (NN * SS)       // 787968 floats per batch slice
#define F4_PER_B (FLOATS_PER_B / 4)  // 196992 float4s per batch slice
#define BLOCKS_PER_B 63              // stride 63*256=16128 float4s ≡ 0 (mod 3)
                                     // -> s-phase p = q%3 is constant per thread
#define THREADS 256

// 16B vector with relaxed 4B alignment (t-window loads are 8B-aligned; HW allows it)
typedef float f4u __attribute__((ext_vector_type(4), aligned(4)));

// --- Kernel 0: zero the 288-float accumulator in workspace (poisoned 0xAA) ---
__global__ void pil_zero_ws(float* __restrict__ ws) {
    int i = threadIdx.x;
    if (i < BB * SS * SS) ws[i] = 0.0f;
}

// --- Kernel 1: accumulate sum_n |est[b,n,i] - tgt[b,n,j]| into ws[b*9+i*3+j] ---
// Fully-coalesced loads: each thread owns ONE float4 per iteration (16B lane
// stride -> each wave load instruction covers a contiguous 1KB block, 16 lines,
// vs 48 scattered lines for the old 48B-stride ownership).
// Each e-float at q+k (s-index i=(q+k)%3) pairs with t[q+k-i .. q+k-i+2], all
// inside the window t[q-2 .. q+5], loaded as two 16B loads at q-2 and q+2.
__global__ __launch_bounds__(THREADS, 8) void pil_partial(
        const float* __restrict__ est,
        const float* __restrict__ tgt,
        float* __restrict__ ws) {
    const int b   = blockIdx.x / BLOCKS_PER_B;
    const int blk = blockIdx.x % BLOCKS_PER_B;
    const float* __restrict__ ef = est + (size_t)b * FLOATS_PER_B;
    const float* __restrict__ tf = tgt + (size_t)b * FLOATS_PER_B;

    const int idx0 = blk * THREADS + threadIdx.x;
    const int p = idx0 % 3;  // == q%3, constant across iterations (stride%3==0)

    // Thread-constant masks, hoisted by the compiler out of the loop.
    const bool p0 = (p == 0), p1 = (p == 1);
    const bool klo1 = (p < 2);  // k=1 uses the low window
    const bool klo2 = (p < 1);  // k=2 uses the low window

    float acc[4][3];
#pragma unroll
    for (int k = 0; k < 4; ++k)
#pragma unroll
        for (int j = 0; j < 3; ++j) acc[k][j] = 0.0f;

    for (int idx = idx0; idx < F4_PER_B; idx += BLOCKS_PER_B * THREADS) {
        const int q = 4 * idx;
        const f4u e4 = *(const f4u*)(ef + q);

        // t-window [q-2, q+5]; clamp only at the true array head/tail
        // (for 0<b<BB-1 the out-of-slice reads land in adjacent slices:
        //  head reads are CORRECT window contents, tail reads are unused slots).
        int qa = q - 2;
        int qb = q + 2;
        const bool fixA = (b == 0) && (q == 0);
        const bool fixB = (b == BB - 1) && (q == FLOATS_PER_B - 4);
        if (fixA) qa = 0;
        if (fixB) qb = FLOATS_PER_B - 4;
        f4u ta  = *(const f4u*)(tf + qa);
        f4u tb4 = *(const f4u*)(tf + qb);
        if (fixA) { ta.z  = ta.x;  ta.w  = ta.y; }   // slots 2,3 := t[0],t[1]
        if (fixB) { tb4.x = tb4.z; tb4.y = tb4.w; }  // slots 4,5 := t[end-2..]

        const float tw[8] = {ta.x, ta.y, ta.z, ta.w, tb4.x, tb4.y, tb4.z, tb4.w};

        // low window = t[3*floor(q/3) ..], high window = next n-group of 3
        float wlo[3], whi[3];
#pragma unroll
        for (int j = 0; j < 3; ++j) {
            wlo[j] = p0 ? tw[2 + j] : (p1 ? tw[1 + j] : tw[0 + j]);
            whi[j] = p0 ? tw[5 + j] : (p1 ? tw[4 + j] : tw[3 + j]);
        }

#pragma unroll
        for (int j = 0; j < 3; ++j) {
            acc[0][j] += fabsf(e4.x - wlo[j]);                    // k=0: always lo
            const float t1 = klo1 ? wlo[j] : whi[j];
            acc[1][j] += fabsf(e4.y - t1);
            const float t2 = klo2 ? wlo[j] : whi[j];
            acc[2][j] += fabsf(e4.z - t2);
            acc[3][j] += fabsf(e4.w - whi[j]);                    // k=3: always hi
        }
    }

    // Remap acc[k][j] -> canonical C[i][j], i=(p+k)%3.
    // k=0 and k=3 share row p; k=1 -> row (p+1)%3; k=2 -> row (p+2)%3.
    float c9[9];
#pragma unroll
    for (int j = 0; j < 3; ++j) {
        const float s03 = acc[0][j] + acc[3][j];
        const float s1  = acc[1][j];
        const float s2  = acc[2][j];
        c9[0 * 3 + j] = p0 ? s03 : (p1 ? s2 : s1);
        c9[1 * 3 + j] = p0 ? s1  : (p1 ? s03 : s2);
        c9[2 * 3 + j] = p0 ? s2  : (p1 ? s1 : s03);
    }

    // Wave-level reduction (64 lanes) of each of the 9 accumulators.
#pragma unroll
    for (int k = 0; k < 9; ++k) {
        float v = c9[k];
#pragma unroll
        for (int off = 32; off > 0; off >>= 1) v += __shfl_down(v, off);
        c9[k] = v;
    }

    __shared__ float sred[THREADS / 64][9];
    const int wave = threadIdx.x >> 6;
    const int lane = threadIdx.x & 63;
    if (lane == 0) {
#pragma unroll
        for (int k = 0; k < 9; ++k) sred[wave][k] = c9[k];
    }
    __syncthreads();

    if (threadIdx.x < 9) {
        float s = 0.0f;
#pragma unroll
        for (int w = 0; w < THREADS / 64; ++w) s += sred[w][threadIdx.x];
        atomicAdd(&ws[b * 9 + threadIdx.x], s);
    }
}

// --- Kernel 2: per-b permutation losses, min over perms, mean over b ---
__global__ void pil_finalize(const float* __restrict__ ws, float* __restrict__ out) {
    const int lane = threadIdx.x;  // 64 threads, lanes >= BB idle
    float loss = 0.0f;
    if (lane < BB) {
        float C[3][3];
#pragma unroll
        for (int i = 0; i < 3; ++i)
#pragma unroll
            for (int j = 0; j < 3; ++j)
                C[i][j] = ws[lane * 9 + i * 3 + j] * (1.0f / (float)NN);

        const int P[6][3] = {{0, 1, 2}, {0, 2, 1}, {1, 0, 2},
                             {1, 2, 0}, {2, 0, 1}, {2, 1, 0}};
        float best = 3.4e38f;
#pragma unroll
        for (int p = 0; p < 6; ++p) {
            float l = (C[P[p][0]][0] + C[P[p][1]][1] + C[P[p][2]][2]) * (1.0f / 3.0f);
            best = fminf(best, l);
        }
        loss = best;
    }
#pragma unroll
    for (int off = 32; off > 0; off >>= 1) loss += __shfl_down(loss, off);
    if (lane == 0) out[0] = loss * (1.0f / (float)BB);
}

extern "C" void kernel_launch(void* const* d_in, const int* in_sizes, int n_in,
                              void* d_out, int out_size, void* d_ws, size_t ws_size,
                              hipStream_t stream) {
    const float* est = (const float*)d_in[0];
    const float* tgt = (const float*)d_in[1];
    float* ws  = (float*)d_ws;
    float* out = (float*)d_out;

    pil_zero_ws<<<1, 320, 0, stream>>>(ws);
    pil_partial<<<BB * BLOCKS_PER_B, THREADS, 0, stream>>>(est, tgt, ws);
    pil_finalize<<<1, 64, 0, stream>>>(ws, out);
}

// Round 3
// 215.214 us; speedup vs baseline: 1.0192x; 1.0192x over previous
//
#include <hip/hip_runtime.h>

// Problem constants (from setup_inputs): B=32, T=512, F=513, S=3
#define BB 32
#define TT 512
#define FF 513
#define SS 3
#define NN (TT * FF)               // 262656 elements per (b, source)
#define FLOATS_PER_B (NN * SS)     // 787968 floats per batch slice (divisible by 12)
#define CHUNKS_PER_B (FLOATS_PER_B / 12)  // 65664 chunks of 12 floats (4 source-groups)
#define PAIRS (CHUNKS_PER_B / 2)   // 32832: thread handles chunks (c, c+PAIRS)
#define BLOCKS_PER_B 64
#define THREADS 256

// --- Kernel 0: zero the 288-float accumulator in workspace (poisoned 0xAA) ---
__global__ void pil_zero_ws(float* __restrict__ ws) {
    int i = threadIdx.x;
    if (i < BB * SS * SS) ws[i] = 0.0f;
}

// --- Kernel 1: accumulate sum_n |est[b,n,i] - tgt[b,n,j]| into ws[b*9+i*3+j] ---
// MLP experiment: 2 chunks (12 aligned dwordx4 = 12KB/wave) issued back-to-back
// per iteration before any use. R0/R1/R2 all equilibrated at ~60KB in-flight/CU
// -> 2.55 TB/s; this version targets ~192KB/CU (16 waves x 12KB).
// launch_bounds(256,4): allow up to ~128 VGPR, don't force spills.
__global__ __launch_bounds__(THREADS, 4) void pil_partial(
        const float* __restrict__ est,
        const float* __restrict__ tgt,
        float* __restrict__ ws) {
    const int b   = blockIdx.x >> 6;   // / BLOCKS_PER_B
    const int blk = blockIdx.x & 63;   // % BLOCKS_PER_B

    const float4* __restrict__ eb = (const float4*)(est + (size_t)b * FLOATS_PER_B);
    const float4* __restrict__ tb = (const float4*)(tgt + (size_t)b * FLOATS_PER_B);

    float acc[9];
#pragma unroll
    for (int k = 0; k < 9; ++k) acc[k] = 0.0f;

    // Pair (c, c+PAIRS): c sweeps [0, PAIRS) -> all chunks covered exactly once.
    // Stride 64*256 = 16384; PAIRS = 32832 -> 2 full iterations (+64-thread tail).
    for (int c = blk * THREADS + threadIdx.x; c < PAIRS;
         c += BLOCKS_PER_B * THREADS) {
        const int a4 = 3 * c;               // chunk A: float4 indices a4..a4+2
        const int b4 = 3 * c + 3 * PAIRS;   // chunk B

        // Issue all 12 loads (192B/thread) before any arithmetic use.
        const float4 eA0 = eb[a4 + 0];
        const float4 eA1 = eb[a4 + 1];
        const float4 eA2 = eb[a4 + 2];
        const float4 tA0 = tb[a4 + 0];
        const float4 tA1 = tb[a4 + 1];
        const float4 tA2 = tb[a4 + 2];
        const float4 eB0 = eb[b4 + 0];
        const float4 eB1 = eb[b4 + 1];
        const float4 eB2 = eb[b4 + 2];
        const float4 tB0 = tb[b4 + 0];
        const float4 tB1 = tb[b4 + 1];
        const float4 tB2 = tb[b4 + 2];

        const float eA[12] = {eA0.x, eA0.y, eA0.z, eA0.w, eA1.x, eA1.y,
                              eA1.z, eA1.w, eA2.x, eA2.y, eA2.z, eA2.w};
        const float tA[12] = {tA0.x, tA0.y, tA0.z, tA0.w, tA1.x, tA1.y,
                              tA1.z, tA1.w, tA2.x, tA2.y, tA2.z, tA2.w};
        const float eB[12] = {eB0.x, eB0.y, eB0.z, eB0.w, eB1.x, eB1.y,
                              eB1.z, eB1.w, eB2.x, eB2.y, eB2.z, eB2.w};
        const float tB[12] = {tB0.x, tB0.y, tB0.z, tB0.w, tB1.x, tB1.y,
                              tB1.z, tB1.w, tB2.x, tB2.y, tB2.z, tB2.w};

#pragma unroll
        for (int g = 0; g < 4; ++g) {
#pragma unroll
            for (int i = 0; i < 3; ++i) {
#pragma unroll
                for (int j = 0; j < 3; ++j) {
                    acc[i * 3 + j] += fabsf(eA[3 * g + i] - tA[3 * g + j]) +
                                      fabsf(eB[3 * g + i] - tB[3 * g + j]);
                }
            }
        }
    }

    // Wave-level reduction (64 lanes) of each of the 9 accumulators.
#pragma unroll
    for (int k = 0; k < 9; ++k) {
        float v = acc[k];
#pragma unroll
        for (int off = 32; off > 0; off >>= 1) v += __shfl_down(v, off);
        acc[k] = v;
    }

    __shared__ float sred[THREADS / 64][9];
    const int wave = threadIdx.x >> 6;
    const int lane = threadIdx.x & 63;
    if (lane == 0) {
#pragma unroll
        for (int k = 0; k < 9; ++k) sred[wave][k] = acc[k];
    }
    __syncthreads();

    if (threadIdx.x < 9) {
        float s = 0.0f;
#pragma unroll
        for (int w = 0; w < THREADS / 64; ++w) s += sred[w][threadIdx.x];
        atomicAdd(&ws[b * 9 + threadIdx.x], s);
    }
}

// --- Kernel 2: per-b permutation losses, min over perms, mean over b ---
__global__ void pil_finalize(const float* __restrict__ ws, float* __restrict__ out) {
    const int lane = threadIdx.x;  // 64 threads, lanes >= BB idle
    float loss = 0.0f;
    if (lane < BB) {
        float C[3][3];
#pragma unroll
        for (int i = 0; i < 3; ++i)
#pragma unroll
            for (int j = 0; j < 3; ++j)
                C[i][j] = ws[lane * 9 + i * 3 + j] * (1.0f / (float)NN);

        const int P[6][3] = {{0, 1, 2}, {0, 2, 1}, {1, 0, 2},
                             {1, 2, 0}, {2, 0, 1}, {2, 1, 0}};
        float best = 3.4e38f;
#pragma unroll
        for (int p = 0; p < 6; ++p) {
            float l = (C[P[p][0]][0] + C[P[p][1]][1] + C[P[p][2]][2]) * (1.0f / 3.0f);
            best = fminf(best, l);
        }
        loss = best;
    }
#pragma unroll
    for (int off = 32; off > 0; off >>= 1) loss += __shfl_down(loss, off);
    if (lane == 0) out[0] = loss * (1.0f / (float)BB);
}

extern "C" void kernel_launch(void* const* d_in, const int* in_sizes, int n_in,
                              void* d_out, int out_size, void* d_ws, size_t ws_size,
                              hipStream_t stream) {
    const float* est = (const float*)d_in[0];
    const float* tgt = (const float*)d_in[1];
    float* ws  = (float*)d_ws;
    float* out = (float*)d_out;

    pil_zero_ws<<<1, 320, 0, stream>>>(ws);
    pil_partial<<<BB * BLOCKS_PER_B, THREADS, 0, stream>>>(est, tgt, ws);
    pil_finalize<<<1, 64, 0, stream>>>(ws, out);
}

// Round 4
// 212.085 us; speedup vs baseline: 1.0343x; 1.0148x over previous
//
#include <hip/hip_runtime.h>

// Problem constants (from setup_inputs): B=32, T=512, F=513, S=3
#define BB 32
#define TT 512
#define FF 513
#define SS 3
#define NN (TT * FF)               // 262656 elements per (b, source)
#define FLOATS_PER_B (NN * SS)     // 787968 floats per batch slice (divisible by 12)
#define CHUNKS_PER_B (FLOATS_PER_B / 12)  // 65664 chunks of 12 floats (4 source-groups)
#define BLOCKS_PER_B 64            // grid 2048 blocks = 8192 waves
#define THREADS 256

// ext_vector float4 (class-type HIP float4 can't feed __builtin_nontemporal_load)
typedef float f4 __attribute__((ext_vector_type(4)));

// --- Kernel 0: zero the 288-float accumulator in workspace (poisoned 0xAA) ---
__global__ void pil_zero_ws(float* __restrict__ ws) {
    int i = threadIdx.x;
    if (i < BB * SS * SS) ws[i] = 0.0f;
}

// --- Kernel 1: accumulate sum_n |est[b,n,i] - tgt[b,n,j]| into ws[b*9+i*3+j] ---
// R4 experiment: NON-TEMPORAL loads on both input streams. R0-R3 established a
// chip-level delivered-BW cap of ~2.6 TB/s independent of occupancy, coalescing
// and per-wave MLP; theory = L3 thrash (202MB cyclic scan through 256MB L3,
// FETCH_SIZE shows a 50/50 HBM/L3 split). nt -> no L2/L3 allocation, pure HBM
// streaming read (~5-6 TB/s for read-only). Data has zero intra-pass reuse, so
// bypassing the caches is semantically free.
__global__ __launch_bounds__(THREADS, 8) void pil_partial(
        const float* __restrict__ est,
        const float* __restrict__ tgt,
        float* __restrict__ ws) {
    const int b   = blockIdx.x >> 6;   // / BLOCKS_PER_B
    const int blk = blockIdx.x & 63;   // % BLOCKS_PER_B

    const f4* __restrict__ eb = (const f4*)(est + (size_t)b * FLOATS_PER_B);
    const f4* __restrict__ tb = (const f4*)(tgt + (size_t)b * FLOATS_PER_B);

    float acc[9];
#pragma unroll
    for (int k = 0; k < 9; ++k) acc[k] = 0.0f;

    // Each chunk c covers float4 indices 3c, 3c+1, 3c+2 => 12 floats = 4 groups of S=3.
    for (int c = blk * THREADS + threadIdx.x; c < CHUNKS_PER_B;
         c += BLOCKS_PER_B * THREADS) {
        const f4 e0 = __builtin_nontemporal_load(eb + 3 * c + 0);
        const f4 e1 = __builtin_nontemporal_load(eb + 3 * c + 1);
        const f4 e2 = __builtin_nontemporal_load(eb + 3 * c + 2);
        const f4 t0 = __builtin_nontemporal_load(tb + 3 * c + 0);
        const f4 t1 = __builtin_nontemporal_load(tb + 3 * c + 1);
        const f4 t2 = __builtin_nontemporal_load(tb + 3 * c + 2);

        const float e[12] = {e0.x, e0.y, e0.z, e0.w, e1.x, e1.y,
                             e1.z, e1.w, e2.x, e2.y, e2.z, e2.w};
        const float t[12] = {t0.x, t0.y, t0.z, t0.w, t1.x, t1.y,
                             t1.z, t1.w, t2.x, t2.y, t2.z, t2.w};
#pragma unroll
        for (int g = 0; g < 4; ++g) {
#pragma unroll
            for (int i = 0; i < 3; ++i) {
#pragma unroll
                for (int j = 0; j < 3; ++j) {
                    acc[i * 3 + j] += fabsf(e[3 * g + i] - t[3 * g + j]);
                }
            }
        }
    }

    // Wave-level reduction (64 lanes) of each of the 9 accumulators.
#pragma unroll
    for (int k = 0; k < 9; ++k) {
        float v = acc[k];
#pragma unroll
        for (int off = 32; off > 0; off >>= 1) v += __shfl_down(v, off);
        acc[k] = v;
    }

    __shared__ float sred[THREADS / 64][9];
    const int wave = threadIdx.x >> 6;
    const int lane = threadIdx.x & 63;
    if (lane == 0) {
#pragma unroll
        for (int k = 0; k < 9; ++k) sred[wave][k] = acc[k];
    }
    __syncthreads();

    if (threadIdx.x < 9) {
        float s = 0.0f;
#pragma unroll
        for (int w = 0; w < THREADS / 64; ++w) s += sred[w][threadIdx.x];
        atomicAdd(&ws[b * 9 + threadIdx.x], s);
    }
}

// --- Kernel 2: per-b permutation losses, min over perms, mean over b ---
__global__ void pil_finalize(const float* __restrict__ ws, float* __restrict__ out) {
    const int lane = threadIdx.x;  // 64 threads, lanes >= BB idle
    float loss = 0.0f;
    if (lane < BB) {
        float C[3][3];
#pragma unroll
        for (int i = 0; i < 3; ++i)
#pragma unroll
            for (int j = 0; j < 3; ++j)
                C[i][j] = ws[lane * 9 + i * 3 + j] * (1.0f / (float)NN);

        const int P[6][3] = {{0, 1, 2}, {0, 2, 1}, {1, 0, 2},
                             {1, 2, 0}, {2, 0, 1}, {2, 1, 0}};
        float best = 3.4e38f;
#pragma unroll
        for (int p = 0; p < 6; ++p) {
            float l = (C[P[p][0]][0] + C[P[p][1]][1] + C[P[p][2]][2]) * (1.0f / 3.0f);
            best = fminf(best, l);
        }
        loss = best;
    }
#pragma unroll
    for (int off = 32; off > 0; off >>= 1) loss += __shfl_down(loss, off);
    if (lane == 0) out[0] = loss * (1.0f / (float)BB);
}

extern "C" void kernel_launch(void* const* d_in, const int* in_sizes, int n_in,
                              void* d_out, int out_size, void* d_ws, size_t ws_size,
                              hipStream_t stream) {
    const float* est = (const float*)d_in[0];
    const float* tgt = (const float*)d_in[1];
    float* ws  = (float*)d_ws;
    float* out = (float*)d_out;

    pil_zero_ws<<<1, 320, 0, stream>>>(ws);
    pil_partial<<<BB * BLOCKS_PER_B, THREADS, 0, stream>>>(est, tgt, ws);
    pil_finalize<<<1, 64, 0, stream>>>(ws, out);
}

// Round 5
// 211.852 us; speedup vs baseline: 1.0354x; 1.0011x over previous
//
#include <hip/hip_runtime.h>

// Problem constants (from setup_inputs): B=32, T=512, F=513, S=3
#define BB 32
#define TT 512
#define FF 513
#define SS 3
#define NN (TT * FF)               // 262656 elements per (b, source)
#define FLOATS_PER_B (NN * SS)     // 787968 floats per batch slice (divisible by 12)
#define CHUNKS_PER_B (FLOATS_PER_B / 12)  // 65664 chunks of 12 floats (4 source-groups)
#define PAIRS (CHUNKS_PER_B / 2)   // 32832: thread handles chunks (c, c+PAIRS)
#define BLOCKS_PER_B 64            // grid 2048 blocks
#define THREADS 256

// ext_vector float4 (class-type HIP float4 can't feed __builtin_nontemporal_load)
typedef float f4 __attribute__((ext_vector_type(4)));

// --- Kernel 1: accumulate sum_n |est[b,n,i] - tgt[b,n,j]| per block into
// ws[(b*64+blk)*9 + i*3+j] (plain store, no atomics, no pre-zero needed).
// R5 experiment: nt loads (R4, proven: partial dropped out of top-5, <58us)
// + 2-chunk MLP (R3 structure): 12 back-to-back nt dwordx4 = 3KB in flight
// per wave. Under nt every load is a full HBM round-trip (~900cy, no L3
// shortening), so BW = outstanding/latency -> per-wave MLP should now pay,
// unlike R3 where the L3-thrash path capped everything at 2.6 TB/s.
__global__ __launch_bounds__(THREADS, 4) void pil_partial(
        const float* __restrict__ est,
        const float* __restrict__ tgt,
        float* __restrict__ ws) {
    const int b   = blockIdx.x >> 6;   // / BLOCKS_PER_B
    const int blk = blockIdx.x & 63;   // % BLOCKS_PER_B

    const f4* __restrict__ eb = (const f4*)(est + (size_t)b * FLOATS_PER_B);
    const f4* __restrict__ tb = (const f4*)(tgt + (size_t)b * FLOATS_PER_B);

    float acc[9];
#pragma unroll
    for (int k = 0; k < 9; ++k) acc[k] = 0.0f;

    // Pair (c, c+PAIRS): c sweeps [0, PAIRS) -> all 65664 chunks exactly once.
    for (int c = blk * THREADS + threadIdx.x; c < PAIRS;
         c += BLOCKS_PER_B * THREADS) {
        const int a4 = 3 * c;               // chunk A: float4 indices a4..a4+2
        const int b4 = 3 * c + 3 * PAIRS;   // chunk B

        // 12 nt loads (192B/thread) issued before any arithmetic use.
        const f4 eA0 = __builtin_nontemporal_load(eb + a4 + 0);
        const f4 eA1 = __builtin_nontemporal_load(eb + a4 + 1);
        const f4 eA2 = __builtin_nontemporal_load(eb + a4 + 2);
        const f4 tA0 = __builtin_nontemporal_load(tb + a4 + 0);
        const f4 tA1 = __builtin_nontemporal_load(tb + a4 + 1);
        const f4 tA2 = __builtin_nontemporal_load(tb + a4 + 2);
        const f4 eB0 = __builtin_nontemporal_load(eb + b4 + 0);
        const f4 eB1 = __builtin_nontemporal_load(eb + b4 + 1);
        const f4 eB2 = __builtin_nontemporal_load(eb + b4 + 2);
        const f4 tB0 = __builtin_nontemporal_load(tb + b4 + 0);
        const f4 tB1 = __builtin_nontemporal_load(tb + b4 + 1);
        const f4 tB2 = __builtin_nontemporal_load(tb + b4 + 2);

        const float eA[12] = {eA0.x, eA0.y, eA0.z, eA0.w, eA1.x, eA1.y,
                              eA1.z, eA1.w, eA2.x, eA2.y, eA2.z, eA2.w};
        const float tA[12] = {tA0.x, tA0.y, tA0.z, tA0.w, tA1.x, tA1.y,
                              tA1.z, tA1.w, tA2.x, tA2.y, tA2.z, tA2.w};
        const float eB[12] = {eB0.x, eB0.y, eB0.z, eB0.w, eB1.x, eB1.y,
                              eB1.z, eB1.w, eB2.x, eB2.y, eB2.z, eB2.w};
        const float tB[12] = {tB0.x, tB0.y, tB0.z, tB0.w, tB1.x, tB1.y,
                              tB1.z, tB1.w, tB2.x, tB2.y, tB2.z, tB2.w};

#pragma unroll
        for (int g = 0; g < 4; ++g) {
#pragma unroll
            for (int i = 0; i < 3; ++i) {
#pragma unroll
                for (int j = 0; j < 3; ++j) {
                    acc[i * 3 + j] += fabsf(eA[3 * g + i] - tA[3 * g + j]) +
                                      fabsf(eB[3 * g + i] - tB[3 * g + j]);
                }
            }
        }
    }

    // Wave-level reduction (64 lanes) of each of the 9 accumulators.
#pragma unroll
    for (int k = 0; k < 9; ++k) {
        float v = acc[k];
#pragma unroll
        for (int off = 32; off > 0; off >>= 1) v += __shfl_down(v, off);
        acc[k] = v;
    }

    __shared__ float sred[THREADS / 64][9];
    const int wave = threadIdx.x >> 6;
    const int lane = threadIdx.x & 63;
    if (lane == 0) {
#pragma unroll
        for (int k = 0; k < 9; ++k) sred[wave][k] = acc[k];
    }
    __syncthreads();

    if (threadIdx.x < 9) {
        float s = 0.0f;
#pragma unroll
        for (int w = 0; w < THREADS / 64; ++w) s += sred[w][threadIdx.x];
        ws[(size_t)blockIdx.x * 9 + threadIdx.x] = s;   // private slot, no atomic
    }
}

// --- Kernel 2: reduce 2048 block-partials -> C[b][i][j], then per-b min over
// the 6 permutations, then mean over b. 320 threads: 288 active for the grid
// reduction, lanes 0..31 of wave 0 for the final per-b min + mean.
__global__ void pil_finalize(const float* __restrict__ ws, float* __restrict__ out) {
    __shared__ float cs[BB][9];
    const int t = threadIdx.x;

    if (t < BB * 9) {
        const int b = t / 9, k = t % 9;
        const float* p = ws + (size_t)b * BLOCKS_PER_B * 9 + k;
        float s = 0.0f;
#pragma unroll 8
        for (int blk = 0; blk < BLOCKS_PER_B; ++blk) s += p[blk * 9];
        cs[b][k] = s;
    }
    __syncthreads();

    if (t < 64) {
        float loss = 0.0f;
        if (t < BB) {
            float C[3][3];
#pragma unroll
            for (int i = 0; i < 3; ++i)
#pragma unroll
                for (int j = 0; j < 3; ++j)
                    C[i][j] = cs[t][i * 3 + j] * (1.0f / (float)NN);

            const int P[6][3] = {{0, 1, 2}, {0, 2, 1}, {1, 0, 2},
                                 {1, 2, 0}, {2, 0, 1}, {2, 1, 0}};
            float best = 3.4e38f;
#pragma unroll
            for (int p = 0; p < 6; ++p) {
                float l = (C[P[p][0]][0] + C[P[p][1]][1] + C[P[p][2]][2]) *
                          (1.0f / 3.0f);
                best = fminf(best, l);
            }
            loss = best;
        }
#pragma unroll
        for (int off = 32; off > 0; off >>= 1) loss += __shfl_down(loss, off);
        if (t == 0) out[0] = loss * (1.0f / (float)BB);
    }
}

extern "C" void kernel_launch(void* const* d_in, const int* in_sizes, int n_in,
                              void* d_out, int out_size, void* d_ws, size_t ws_size,
                              hipStream_t stream) {
    const float* est = (const float*)d_in[0];
    const float* tgt = (const float*)d_in[1];
    float* ws  = (float*)d_ws;
    float* out = (float*)d_out;

    pil_partial<<<BB * BLOCKS_PER_B, THREADS, 0, stream>>>(est, tgt, ws);
    pil_finalize<<<1, 320, 0, stream>>>(ws, out);
}